// Round 4
// baseline (1831.952 us; speedup 1.0000x reference)
//
#include <hip/hip_runtime.h>
#include <stdint.h>

// Problem constants (fixed by the reference)
#define NN 50000
#define EE 800000
#define INDIM 1280
#define GD 512
#define CAT 1536
#define FC0D 1024
#define FC1D 512
#define OUTD 256
#define NG 64

typedef __attribute__((ext_vector_type(8))) __bf16 bf16x8;
typedef __attribute__((ext_vector_type(4))) float f32x4;
typedef __attribute__((ext_vector_type(8))) unsigned short u16x8;

// ---------------- helpers ----------------
__device__ __forceinline__ void split_bf16(float f, unsigned short& h, unsigned short& l) {
    unsigned int u = __builtin_bit_cast(unsigned int, f);
    h = (unsigned short)(u >> 16);                       // truncated hi
    float hf = __builtin_bit_cast(float, u & 0xffff0000u);
    float lf = f - hf;                                   // exact residual
    unsigned int ul = __builtin_bit_cast(unsigned int, lf);
    ul = ul + 0x7fffu + ((ul >> 16) & 1u);               // RNE lo
    l = (unsigned short)(ul >> 16);
}

__device__ __forceinline__ float bf2f(unsigned short s) {
    return __builtin_bit_cast(float, (unsigned int)s << 16);
}

__device__ __forceinline__ void g2l16(const void* g, void* l) {
    __builtin_amdgcn_global_load_lds(
        (const __attribute__((address_space(1))) void*)g,
        (__attribute__((address_space(3))) void*)l, 16, 0, 0);
}

// ---------------- utility kernels ----------------
__global__ void zero_u32(uint32_t* p, int n) {
    int i = blockIdx.x * 256 + threadIdx.x;
    if (i < n) p[i] = 0u;
}

__global__ void count_edges(const int* __restrict__ ei, int* __restrict__ cnt) {
    int e = blockIdx.x * 256 + threadIdx.x;
    if (e < EE) atomicAdd(&cnt[ei[EE + e]], 1);
}

__global__ __launch_bounds__(1024) void scan1(const int* __restrict__ cnt,
                                              int* __restrict__ row_ptr,
                                              int* __restrict__ bsum, int n) {
    __shared__ int s[1024];
    int tid = threadIdx.x;
    int i = blockIdx.x * 1024 + tid;
    int v = (i < n) ? cnt[i] : 0;
    s[tid] = v;
    __syncthreads();
    for (int off = 1; off < 1024; off <<= 1) {
        int t = 0;
        if (tid >= off) t = s[tid - off];
        __syncthreads();
        if (tid >= off) s[tid] += t;
        __syncthreads();
    }
    if (i < n) row_ptr[i] = s[tid] - v;
    if (tid == 1023) bsum[blockIdx.x] = s[1023];
}

// wave-parallel exclusive scan of nb (<=64) block sums
__global__ void scan2(int* bsum, int nb) {
    int i = threadIdx.x;   // 64 threads
    int v = (i < nb) ? bsum[i] : 0;
    int s = v;
#pragma unroll
    for (int off = 1; off < 64; off <<= 1) {
        int t = __shfl_up(s, off);
        if (i >= off) s += t;
    }
    if (i < nb) bsum[i] = s - v;
}

// row_ptr += block offset; also emit dinv and fill
__global__ __launch_bounds__(1024) void scan3(int* __restrict__ row_ptr,
                                              const int* __restrict__ bsum,
                                              const int* __restrict__ cnt,
                                              float* __restrict__ dinv,
                                              int* __restrict__ fill, int n) {
    int i = blockIdx.x * 1024 + threadIdx.x;
    if (i < n) {
        int rp = row_ptr[i] + bsum[blockIdx.x];
        row_ptr[i] = rp;
        fill[i] = rp;
        dinv[i] = rsqrtf((float)cnt[i] + 1.0f);
    }
    if (i == 0) row_ptr[n] = EE;
}

__global__ void scatter_edges(const int* __restrict__ ei, int* __restrict__ fill,
                              int* __restrict__ col) {
    int e = blockIdx.x * 256 + threadIdx.x;
    if (e < EE) {
        int s = ei[e];
        int d = ei[EE + e];
        int pos = atomicAdd(&fill[d], 1);
        col[pos] = s;
    }
}

__global__ void count_batch(const int* __restrict__ batch, int* __restrict__ gcnt) {
    int i = blockIdx.x * 256 + threadIdx.x;
    if (i < NN) atomicAdd(&gcnt[batch[i]], 1);
}

// wave-parallel scan of the 64 graph counts
__global__ void gscan(const int* __restrict__ gcnt, int* __restrict__ goff) {
    int i = threadIdx.x;   // 64 threads
    int v = gcnt[i];
    int s = v;
#pragma unroll
    for (int off = 1; off < 64; off <<= 1) {
        int t = __shfl_up(s, off);
        if (i >= off) s += t;
    }
    goff[i] = s - v;
    if (i == 63) goff[64] = s;
}

// ---------------- scalar aggregation: vout = A_hat * vin (vin==null -> ones) ----------
__global__ void sagg(const int* __restrict__ row_ptr, const int* __restrict__ col,
                     const float* __restrict__ dinv, const float* __restrict__ vin,
                     float* __restrict__ vout) {
    int i = blockIdx.x * 256 + threadIdx.x;
    if (i >= NN) return;
    float di = dinv[i];
    int s = row_ptr[i], e = row_ptr[i + 1];
    float acc = 0.f;
    for (int t = s; t < e; t++) {
        int c = col[t];
        float v = vin ? vin[c] : 1.0f;
        acc += dinv[c] * v;
    }
    float self = vin ? vin[i] : 1.0f;
    vout[i] = di * acc + di * di * self;
}

// per-graph mean of s1, s2
__global__ __launch_bounds__(256) void pool_s(const float* __restrict__ s1,
                                              const float* __restrict__ s2,
                                              const int* __restrict__ goff,
                                              const int* __restrict__ gcnt,
                                              float* __restrict__ sig1,
                                              float* __restrict__ sig2) {
    int g = blockIdx.x;
    int tid = threadIdx.x;
    int s = goff[g], e = goff[g + 1];
    float a1 = 0.f, a2 = 0.f;
    for (int i = s + tid; i < e; i += 256) { a1 += s1[i]; a2 += s2[i]; }
    __shared__ float r1[256], r2[256];
    r1[tid] = a1; r2[tid] = a2;
    __syncthreads();
    for (int off = 128; off > 0; off >>= 1) {
        if (tid < off) { r1[tid] += r1[tid + off]; r2[tid] += r2[tid + off]; }
        __syncthreads();
    }
    if (tid == 0) {
        float inv = 1.0f / (float)max(gcnt[g], 1);
        sig1[g] = r1[0] * inv;
        sig2[g] = r2[0] * inv;
    }
}

// ---------------- split fp32 -> bf16 hi/lo (flat) ----------------
__global__ void split_x_kernel(const float* __restrict__ x,
                               unsigned short* __restrict__ hi,
                               unsigned short* __restrict__ lo, int n4) {
    int stride = gridDim.x * 256;
    for (int i = blockIdx.x * 256 + threadIdx.x; i < n4; i += stride) {
        float4 v = ((const float4*)x)[i];
        ushort4 h4, l4;
        split_bf16(v.x, h4.x, l4.x);
        split_bf16(v.y, h4.y, l4.y);
        split_bf16(v.z, h4.z, l4.z);
        split_bf16(v.w, h4.w, l4.w);
        ((ushort4*)hi)[i] = h4;
        ((ushort4*)lo)[i] = l4;
    }
}

// ---------------- W [K][512] -> Wt hi/lo [512][K] (transpose + split) ----------------
__global__ __launch_bounds__(256) void tsplit_kernel(const float* __restrict__ W,
                                                     unsigned short* __restrict__ Thi,
                                                     unsigned short* __restrict__ Tlo,
                                                     int K) {
    __shared__ float t[32][33];
    int k0 = blockIdx.x * 32, n0 = blockIdx.y * 32;
    int r = threadIdx.x >> 3;
    int c4 = (threadIdx.x & 7) * 4;
    float4 v = *(const float4*)(W + (size_t)(k0 + r) * GD + n0 + c4);
    t[r][c4 + 0] = v.x;
    t[r][c4 + 1] = v.y;
    t[r][c4 + 2] = v.z;
    t[r][c4 + 3] = v.w;
    __syncthreads();
    ushort4 h4, l4;
    split_bf16(t[c4 + 0][r], h4.x, l4.x);
    split_bf16(t[c4 + 1][r], h4.y, l4.y);
    split_bf16(t[c4 + 2][r], h4.z, l4.z);
    split_bf16(t[c4 + 3][r], h4.w, l4.w);
    *(ushort4*)(Thi + (size_t)(n0 + r) * K + k0 + c4) = h4;
    *(ushort4*)(Tlo + (size_t)(n0 + r) * K + k0 + c4) = l4;
}

// ---------------- split-bf16 MFMA GEMM (layer-1 only now) ----------------
#define GBM 128
#define GBN 256
#define GBK 32

__global__ __launch_bounds__(256, 2) void gemm_split(
    const unsigned short* __restrict__ Ahi, const unsigned short* __restrict__ Alo,
    const unsigned short* __restrict__ Whi, const unsigned short* __restrict__ Wlo,
    unsigned short* __restrict__ Chi, unsigned short* __restrict__ Clo,
    int M, int K) {
    __shared__ __align__(16) char sAh[GBM * GBK * 2];
    __shared__ __align__(16) char sAl[GBM * GBK * 2];
    __shared__ __align__(16) char sBh[GBN * GBK * 2];
    __shared__ __align__(16) char sBl[GBN * GBK * 2];

    const int tid = threadIdx.x;
    const int lane = tid & 63, wid = tid >> 6;
    const int wm = (wid >> 1) * 64;
    const int wn = (wid & 1) * 128;

    // bijective XCD-chunked swizzle (m204)
    const int nwg = gridDim.x;
    const int q = nwg >> 3, r8 = nwg & 7;
    const int xcd = blockIdx.x & 7, slot = blockIdx.x >> 3;
    const int w = (xcd < r8 ? xcd * (q + 1) : r8 * (q + 1) + (xcd - r8) * q) + slot;
    const int bm = (w >> 1) * GBM;
    const int bn = (w & 1) * GBN;

    int ar0 = tid >> 2;
    int ak0 = ((tid & 3) ^ ((ar0 >> 1) & 3)) * 8;
    int ar1 = (tid + 256) >> 2;
    int ak1 = ((tid & 3) ^ ((ar1 >> 1) & 3)) * 8;
    unsigned int aoff0 = (unsigned int)min(bm + ar0, M - 1) * K + ak0;
    unsigned int aoff1 = (unsigned int)min(bm + ar1, M - 1) * K + ak1;
    unsigned int woff[4];
#pragma unroll
    for (int i = 0; i < 4; i++) {
        int p = tid + i * 256;
        int row = p >> 2;
        int ks = ((p & 3) ^ ((row >> 1) & 3)) * 8;
        woff[i] = (unsigned int)(bn + row) * K + ks;
    }

    int aRd[4], bRd[8];
#pragma unroll
    for (int mf = 0; mf < 4; mf++) {
        int row = wm + mf * 16 + (lane & 15);
        aRd[mf] = row * 64 + ((((lane >> 4)) ^ ((row >> 1) & 3)) << 4);
    }
#pragma unroll
    for (int nf = 0; nf < 8; nf++) {
        int row = wn + nf * 16 + (lane & 15);
        bRd[nf] = row * 64 + ((((lane >> 4)) ^ ((row >> 1) & 3)) << 4);
    }

    f32x4 acc[4][8];
#pragma unroll
    for (int mf = 0; mf < 4; mf++)
#pragma unroll
        for (int nf = 0; nf < 8; nf++) acc[mf][nf] = (f32x4)0.0f;

    const int ldsw = wid * 1024;

    for (int k0 = 0; k0 < K; k0 += GBK) {
        __syncthreads();
        g2l16(Ahi + aoff0, sAh + ldsw);
        g2l16(Ahi + aoff1, sAh + 4096 + ldsw);
        g2l16(Alo + aoff0, sAl + ldsw);
        g2l16(Alo + aoff1, sAl + 4096 + ldsw);
#pragma unroll
        for (int i = 0; i < 4; i++) {
            g2l16(Whi + woff[i], sBh + i * 4096 + ldsw);
            g2l16(Wlo + woff[i], sBl + i * 4096 + ldsw);
        }
        aoff0 += GBK; aoff1 += GBK;
#pragma unroll
        for (int i = 0; i < 4; i++) woff[i] += GBK;
        __syncthreads();

        bf16x8 ah[4], al[4];
#pragma unroll
        for (int mf = 0; mf < 4; mf++) {
            ah[mf] = *(const bf16x8*)(sAh + aRd[mf]);
            al[mf] = *(const bf16x8*)(sAl + aRd[mf]);
        }
#pragma unroll
        for (int nf = 0; nf < 8; nf++) {
            bf16x8 bh = *(const bf16x8*)(sBh + bRd[nf]);
            bf16x8 bl = *(const bf16x8*)(sBl + bRd[nf]);
#pragma unroll
            for (int mf = 0; mf < 4; mf++) {
                acc[mf][nf] = __builtin_amdgcn_mfma_f32_16x16x32_bf16(ah[mf], bh, acc[mf][nf], 0, 0, 0);
                acc[mf][nf] = __builtin_amdgcn_mfma_f32_16x16x32_bf16(ah[mf], bl, acc[mf][nf], 0, 0, 0);
                acc[mf][nf] = __builtin_amdgcn_mfma_f32_16x16x32_bf16(al[mf], bh, acc[mf][nf], 0, 0, 0);
            }
        }
    }

#pragma unroll
    for (int mf = 0; mf < 4; mf++) {
        int r0 = bm + wm + mf * 16 + (lane >> 4) * 4;
#pragma unroll
        for (int nf = 0; nf < 8; nf++) {
            int c = bn + wn + nf * 16 + (lane & 15);
#pragma unroll
            for (int r = 0; r < 4; r++) {
                if (r0 + r < M) {
                    unsigned short h, l;
                    split_bf16(acc[mf][nf][r], h, l);
                    Chi[(size_t)(r0 + r) * GD + c] = h;
                    Clo[(size_t)(r0 + r) * GD + c] = l;
                }
            }
        }
    }
}

// ---------------- GCN aggregation (wave per row, bias-free) ----------------
// self term: full precision (Phi+Plo). neighbor gather: bf16 hi only.
__global__ __launch_bounds__(256) void agg_v4(const unsigned short* __restrict__ Phi,
                                              const unsigned short* __restrict__ Plo,
                                              const int* __restrict__ row_ptr,
                                              const int* __restrict__ col,
                                              const float* __restrict__ dinv,
                                              unsigned short* __restrict__ Ohi,
                                              unsigned short* __restrict__ Olo) {
    int wid = threadIdx.x >> 6, lane = threadIdx.x & 63;
    int row = blockIdx.x * 4 + wid;
    if (row >= NN) return;
    float di = dinv[row];
    float self = di * di;

    u16x8 sh = *(const u16x8*)(Phi + (size_t)row * GD + lane * 8);
    u16x8 sl = *(const u16x8*)(Plo + (size_t)row * GD + lane * 8);
    float a[8];
#pragma unroll
    for (int j = 0; j < 8; j++) a[j] = (bf2f(sh[j]) + bf2f(sl[j])) * self;

    int s = row_ptr[row], e = row_ptr[row + 1];
    int t = s;
    for (; t + 3 < e; t += 4) {
        int c0 = col[t], c1 = col[t + 1], c2 = col[t + 2], c3 = col[t + 3];
        float w0 = dinv[c0] * di, w1 = dinv[c1] * di;
        float w2 = dinv[c2] * di, w3 = dinv[c3] * di;
        u16x8 v0 = *(const u16x8*)(Phi + (size_t)c0 * GD + lane * 8);
        u16x8 v1 = *(const u16x8*)(Phi + (size_t)c1 * GD + lane * 8);
        u16x8 v2 = *(const u16x8*)(Phi + (size_t)c2 * GD + lane * 8);
        u16x8 v3 = *(const u16x8*)(Phi + (size_t)c3 * GD + lane * 8);
#pragma unroll
        for (int j = 0; j < 8; j++) {
            a[j] = fmaf(bf2f(v0[j]), w0, a[j]);
            a[j] = fmaf(bf2f(v1[j]), w1, a[j]);
            a[j] = fmaf(bf2f(v2[j]), w2, a[j]);
            a[j] = fmaf(bf2f(v3[j]), w3, a[j]);
        }
    }
    for (; t < e; t++) {
        int c0 = col[t];
        float w0 = dinv[c0] * di;
        u16x8 v0 = *(const u16x8*)(Phi + (size_t)c0 * GD + lane * 8);
#pragma unroll
        for (int j = 0; j < 8; j++) a[j] = fmaf(bf2f(v0[j]), w0, a[j]);
    }

    u16x8 oh, ol;
#pragma unroll
    for (int j = 0; j < 8; j++) {
        unsigned short h, l;
        split_bf16(a[j], h, l);
        oh[j] = h;
        ol[j] = l;
    }
    *(u16x8*)(Ohi + (size_t)row * GD + lane * 8) = oh;
    *(u16x8*)(Olo + (size_t)row * GD + lane * 8) = ol;
}

// ---------------- mean-pool (sum phase, atomic into gsum) from hi/lo ------------
#define PCH 32
__global__ void pool_kernel(const unsigned short* __restrict__ hi,
                            const unsigned short* __restrict__ lo,
                            const int* __restrict__ goff,
                            float* __restrict__ gsum, int coloff) {
    int g = blockIdx.x;
    int c = blockIdx.y;
    int tid = threadIdx.x;
    int s = goff[g], e = goff[g + 1];
    long long len = e - s;
    int cs = s + (int)(len * c / PCH);
    int ce = s + (int)(len * (c + 1) / PCH);
    float a0 = 0.f, a1 = 0.f;
    for (int i = cs; i < ce; i++) {
        unsigned int uh = ((const unsigned int*)(hi + (size_t)i * GD))[tid];
        unsigned int ul = ((const unsigned int*)(lo + (size_t)i * GD))[tid];
        float v0 = __builtin_bit_cast(float, uh << 16) + __builtin_bit_cast(float, ul << 16);
        float v1 = __builtin_bit_cast(float, uh & 0xffff0000u) +
                   __builtin_bit_cast(float, ul & 0xffff0000u);
        a0 += v0;
        a1 += v1;
    }
    if (cs < ce) {
        atomicAdd(&gsum[(size_t)g * CAT + coloff + tid * 2], a0);
        atomicAdd(&gsum[(size_t)g * CAT + coloff + tid * 2 + 1], a1);
    }
}

// ---------------- head prep: g1 slice + t2/t3 inputs -------------------------
__global__ __launch_bounds__(256) void head_prep(const float* __restrict__ gsum,
                                                 const int* __restrict__ gcnt,
                                                 const float* __restrict__ sig1,
                                                 const float* __restrict__ sig2,
                                                 const float* __restrict__ b1,
                                                 float* __restrict__ G,
                                                 float* __restrict__ t2,
                                                 float* __restrict__ t3) {
    int g = blockIdx.x;
    int tid = threadIdx.x;
    float inv = 1.0f / (float)max(gcnt[g], 1);
    float sg1 = sig1[g], sg2 = sig2[g];
    for (int c = tid; c < GD; c += 256) {
        float b = b1[c];
        G[(size_t)g * CAT + c] = gsum[(size_t)g * CAT + c] * inv + b;
        t2[(size_t)g * GD + c] = gsum[(size_t)g * CAT + GD + c] * inv + sg1 * b;
        t3[(size_t)g * GD + c] = gsum[(size_t)g * CAT + 2 * GD + c] * inv + sg2 * b;
    }
}

// ---------------- small f32 GEMM [64x512] @ [512x512] (+ outer/bias terms) -------
// out[m*ostride + c] = sum_k A[m*512+k] W[k*512+c] + (scale? scale[m]*bvec[c]:0) + (cvec? cvec[c]:0)
template <bool HAS_SCALE, bool HAS_CVEC>
__global__ __launch_bounds__(256) void small_mm(const float* __restrict__ A,
                                                const float* __restrict__ W,
                                                const float* __restrict__ scale,
                                                const float* __restrict__ bvec,
                                                const float* __restrict__ cvec,
                                                float* __restrict__ out, int ostride) {
    __shared__ float a_s[64][33];
    int tid = threadIdx.x;
    int c = blockIdx.x * 64 + (tid & 63);
    int grp = tid >> 6;
    float acc[16];
#pragma unroll
    for (int i = 0; i < 16; i++) acc[i] = 0.f;
    for (int k0 = 0; k0 < GD; k0 += 32) {
        __syncthreads();
#pragma unroll
        for (int i = 0; i < 8; i++) {
            int idx = tid + i * 256;
            int m = idx >> 5, kk = idx & 31;
            a_s[m][kk] = A[(size_t)m * GD + k0 + kk];
        }
        __syncthreads();
#pragma unroll
        for (int kk = 0; kk < 32; kk++) {
            float w = W[(size_t)(k0 + kk) * GD + c];
#pragma unroll
            for (int i = 0; i < 16; i++)
                acc[i] = fmaf(a_s[grp * 16 + i][kk], w, acc[i]);
        }
    }
    float bv = HAS_SCALE ? bvec[c] : 0.f;
    float cv = HAS_CVEC ? cvec[c] : 0.f;
#pragma unroll
    for (int i = 0; i < 16; i++) {
        int m = grp * 16 + i;
        float v = acc[i] + cv;
        if (HAS_SCALE) v += scale[m] * bv;
        out[(size_t)m * ostride + c] = v;
    }
}

// ---------------- small FC: out[64 x NOUT] = act(A[64 x K] @ W + b) ----------------
template <int K, int NOUT, bool RELU>
__global__ __launch_bounds__(256) void fc_kernel(const float* __restrict__ A,
                                                 const float* __restrict__ W,
                                                 const float* __restrict__ bias,
                                                 float* __restrict__ out) {
    __shared__ float a_s[64][33];
    int tid = threadIdx.x;
    int c = blockIdx.x * 64 + (tid & 63);
    int grp = tid >> 6;
    float acc[16];
#pragma unroll
    for (int i = 0; i < 16; i++) acc[i] = 0.f;
    for (int k0 = 0; k0 < K; k0 += 32) {
        __syncthreads();
#pragma unroll
        for (int i = 0; i < 8; i++) {
            int idx = tid + i * 256;
            int m = idx >> 5, kk = idx & 31;
            a_s[m][kk] = A[(size_t)m * K + k0 + kk];
        }
        __syncthreads();
#pragma unroll
        for (int kk = 0; kk < 32; kk++) {
            float w = W[(size_t)(k0 + kk) * NOUT + c];
#pragma unroll
            for (int i = 0; i < 16; i++)
                acc[i] = fmaf(a_s[grp * 16 + i][kk], w, acc[i]);
        }
    }
    float b = bias[c];
#pragma unroll
    for (int i = 0; i < 16; i++) {
        float v = acc[i] + b;
        if (RELU) v = fmaxf(v, 0.f);
        out[(size_t)(grp * 16 + i) * NOUT + c] = v;
    }
}

// ---------------- launch ----------------
static inline size_t al256(size_t x) { return (x + 255) & ~(size_t)255; }

extern "C" void kernel_launch(void* const* d_in, const int* in_sizes, int n_in,
                              void* d_out, int out_size, void* d_ws, size_t ws_size,
                              hipStream_t stream) {
    const float* x   = (const float*)d_in[0];
    const int*   ei  = (const int*)d_in[1];
    const int*   bat = (const int*)d_in[2];
    const float* Wg1 = (const float*)d_in[3];
    const float* bg1 = (const float*)d_in[4];
    const float* Wg2 = (const float*)d_in[5];
    const float* bg2 = (const float*)d_in[6];
    const float* Wg3 = (const float*)d_in[7];
    const float* bg3 = (const float*)d_in[8];
    const float* Wr  = (const float*)d_in[9];
    const float* br  = (const float*)d_in[10];
    const float* Wf  = (const float*)d_in[11];
    const float* bf  = (const float*)d_in[12];
    const float* Wo  = (const float*)d_in[13];
    const float* bo  = (const float*)d_in[14];
    float* out = (float*)d_out;

    char* ws = (char*)d_ws;
    size_t off = 0;
    unsigned short* xhi = (unsigned short*)(ws + off); off += al256((size_t)NN * INDIM * 2);
    unsigned short* xlo = (unsigned short*)(ws + off); off += al256((size_t)NN * INDIM * 2);
    unsigned short* Ahi = (unsigned short*)(ws + off); off += al256((size_t)NN * GD * 2);  // Y / Z2
    unsigned short* Alo = (unsigned short*)(ws + off); off += al256((size_t)NN * GD * 2);
    unsigned short* Bhi = (unsigned short*)(ws + off); off += al256((size_t)NN * GD * 2);  // Z1 / Z3
    unsigned short* Blo = (unsigned short*)(ws + off); off += al256((size_t)NN * GD * 2);
    unsigned short* Wt1h = (unsigned short*)(ws + off); off += al256((size_t)GD * INDIM * 2);
    unsigned short* Wt1l = (unsigned short*)(ws + off); off += al256((size_t)GD * INDIM * 2);
    int*   cnt = (int*)(ws + off); off += al256((size_t)NN * 4);
    int*   row_ptr = (int*)(ws + off); off += al256((size_t)(NN + 1) * 4);
    int*   fill = (int*)(ws + off); off += al256((size_t)NN * 4);
    float* dinv = (float*)(ws + off); off += al256((size_t)NN * 4);
    int*   col = (int*)(ws + off); off += al256((size_t)EE * 4);
    int*   bsum = (int*)(ws + off); off += al256(64 * 4);
    int*   gcnt = (int*)(ws + off); off += al256(NG * 4);
    int*   goff = (int*)(ws + off); off += al256((NG + 1) * 4);
    float* s1 = (float*)(ws + off); off += al256((size_t)NN * 4);
    float* s2 = (float*)(ws + off); off += al256((size_t)NN * 4);
    float* sig1 = (float*)(ws + off); off += al256(NG * 4);
    float* sig2 = (float*)(ws + off); off += al256(NG * 4);
    float* gsum = (float*)(ws + off); off += al256((size_t)NG * CAT * 4);
    float* G = (float*)(ws + off); off += al256((size_t)NG * CAT * 4);
    float* t2 = (float*)(ws + off); off += al256((size_t)NG * GD * 4);
    float* t3 = (float*)(ws + off); off += al256((size_t)NG * GD * 4);
    float* u3 = (float*)(ws + off); off += al256((size_t)NG * GD * 4);
    float* r0 = (float*)(ws + off); off += al256((size_t)NG * FC0D * 4);
    float* r1 = (float*)(ws + off); off += al256((size_t)NG * FC1D * 4);
    (void)ws_size; (void)n_in; (void)in_sizes; (void)out_size;

    const int nscan = (NN + 1023) / 1024;

    // zero: cnt, gcnt, gsum
    zero_u32<<<dim3((NN + 255) / 256), 256, 0, stream>>>((uint32_t*)cnt, NN);
    zero_u32<<<dim3(1), 256, 0, stream>>>((uint32_t*)gcnt, NG);
    zero_u32<<<dim3((NG * CAT + 255) / 256), 256, 0, stream>>>((uint32_t*)gsum, NG * CAT);

    // CSR build (by dst)
    count_edges<<<dim3((EE + 255) / 256), 256, 0, stream>>>(ei, cnt);
    scan1<<<dim3(nscan), 1024, 0, stream>>>(cnt, row_ptr, bsum, NN);
    scan2<<<dim3(1), 64, 0, stream>>>(bsum, nscan);
    scan3<<<dim3(nscan), 1024, 0, stream>>>(row_ptr, bsum, cnt, dinv, fill, NN);
    scatter_edges<<<dim3((EE + 255) / 256), 256, 0, stream>>>(ei, fill, col);

    // graph segments
    count_batch<<<dim3((NN + 255) / 256), 256, 0, stream>>>(bat, gcnt);
    gscan<<<dim3(1), 64, 0, stream>>>(gcnt, goff);

    // scalar aggregations s1 = A_hat 1, s2 = A_hat s1, then per-graph means
    sagg<<<dim3((NN + 255) / 256), 256, 0, stream>>>(row_ptr, col, dinv, nullptr, s1);
    sagg<<<dim3((NN + 255) / 256), 256, 0, stream>>>(row_ptr, col, dinv, s1, s2);
    pool_s<<<dim3(NG), 256, 0, stream>>>(s1, s2, goff, gcnt, sig1, sig2);

    // precompute: split x, transpose+split W1
    split_x_kernel<<<dim3(2048), 256, 0, stream>>>(x, xhi, xlo, NN * INDIM / 4);
    tsplit_kernel<<<dim3(INDIM / 32, GD / 32), 256, 0, stream>>>(Wg1, Wt1h, Wt1l, INDIM);

    const int nwg = ((NN + GBM - 1) / GBM) * (GD / GBN);   // 782
    dim3 agrid((NN + 3) / 4);
    dim3 pgrid(NG, PCH);

    // Y = X W1 (the only big GEMM)
    gemm_split<<<dim3(nwg), 256, 0, stream>>>(xhi, xlo, Wt1h, Wt1l, Ahi, Alo, NN, INDIM);
    // Z1 = A_hat Y ; pool
    agg_v4<<<agrid, 256, 0, stream>>>(Ahi, Alo, row_ptr, col, dinv, Bhi, Blo);
    pool_kernel<<<pgrid, 256, 0, stream>>>(Bhi, Blo, goff, gsum, 0);
    // Z2 = A_hat Z1 ; pool
    agg_v4<<<agrid, 256, 0, stream>>>(Bhi, Blo, row_ptr, col, dinv, Ahi, Alo);
    pool_kernel<<<pgrid, 256, 0, stream>>>(Ahi, Alo, goff, gsum, GD);
    // Z3 = A_hat Z2 ; pool
    agg_v4<<<agrid, 256, 0, stream>>>(Ahi, Alo, row_ptr, col, dinv, Bhi, Blo);
    pool_kernel<<<pgrid, 256, 0, stream>>>(Bhi, Blo, goff, gsum, 2 * GD);

    // head algebra:
    // g1 = p1 + b1
    // g2 = (p2 + sig1*b1) W2 + b2
    // g3 = ((p3 + sig2*b1) W2 + sig1*b2) W3 + b3
    head_prep<<<dim3(NG), 256, 0, stream>>>(gsum, gcnt, sig1, sig2, bg1, G, t2, t3);
    small_mm<false, true><<<dim3(GD / 64), 256, 0, stream>>>(t2, Wg2, nullptr, nullptr, bg2, G + GD, CAT);
    small_mm<true, false><<<dim3(GD / 64), 256, 0, stream>>>(t3, Wg2, sig1, bg2, nullptr, u3, GD);
    small_mm<false, true><<<dim3(GD / 64), 256, 0, stream>>>(u3, Wg3, nullptr, nullptr, bg3, G + 2 * GD, CAT);

    // FC head
    fc_kernel<CAT, FC0D, true><<<dim3(FC0D / 64), 256, 0, stream>>>(G, Wr, br, r0);
    fc_kernel<FC0D, FC1D, true><<<dim3(FC1D / 64), 256, 0, stream>>>(r0, Wf, bf, r1);
    fc_kernel<FC1D, OUTD, false><<<dim3(OUTD / 64), 256, 0, stream>>>(r1, Wo, bo, out);
}

// Round 5
// 1758.346 us; speedup vs baseline: 1.0419x; 1.0419x over previous
//
#include <hip/hip_runtime.h>
#include <stdint.h>

// Problem constants (fixed by the reference)
#define NN 50000
#define EE 800000
#define INDIM 1280
#define GD 512
#define CAT 1536
#define FC0D 1024
#define FC1D 512
#define OUTD 256
#define NG 64

// contraction split-K geometry
#define KS 36
#define RS 1440                 // KS*RS = 51840 >= NN, RS % 32 == 0
#define NPAD (KS * RS)          // 51840
#define QSZ (192 * INDIM)       // 245760

__device__ __forceinline__ void g2l16(const void* g, void* l) {
    __builtin_amdgcn_global_load_lds(
        (const __attribute__((address_space(1))) void*)g,
        (__attribute__((address_space(3))) void*)l, 16, 0, 0);
}

// ---------------- utility kernels ----------------
__global__ void zero_u32(uint32_t* p, int n) {
    int i = blockIdx.x * 256 + threadIdx.x;
    if (i < n) p[i] = 0u;
}

// count out-degree (by src) for CSR and in-degree (by dst) for dinv
__global__ void hist_edges(const int* __restrict__ ei, int* __restrict__ cnt_s,
                           int* __restrict__ cnt_d) {
    int e = blockIdx.x * 256 + threadIdx.x;
    if (e < EE) {
        atomicAdd(&cnt_s[ei[e]], 1);
        atomicAdd(&cnt_d[ei[EE + e]], 1);
    }
}

__global__ void count_batch(const int* __restrict__ batch, int* __restrict__ gcnt) {
    int i = blockIdx.x * 256 + threadIdx.x;
    if (i < NN) atomicAdd(&gcnt[batch[i]], 1);
}

__global__ __launch_bounds__(1024) void scan1(const int* __restrict__ cnt,
                                              int* __restrict__ row_ptr,
                                              int* __restrict__ bsum, int n) {
    __shared__ int s[1024];
    int tid = threadIdx.x;
    int i = blockIdx.x * 1024 + tid;
    int v = (i < n) ? cnt[i] : 0;
    s[tid] = v;
    __syncthreads();
    for (int off = 1; off < 1024; off <<= 1) {
        int t = 0;
        if (tid >= off) t = s[tid - off];
        __syncthreads();
        if (tid >= off) s[tid] += t;
        __syncthreads();
    }
    if (i < n) row_ptr[i] = s[tid] - v;
    if (tid == 1023) bsum[blockIdx.x] = s[1023];
}

// wave-parallel exclusive scan of nb (<=64) block sums
__global__ void scan2(int* bsum, int nb) {
    int i = threadIdx.x;
    int v = (i < nb) ? bsum[i] : 0;
    int s = v;
#pragma unroll
    for (int off = 1; off < 64; off <<= 1) {
        int t = __shfl_up(s, off);
        if (i >= off) s += t;
    }
    if (i < nb) bsum[i] = s - v;
}

// finalize row_ptr (by src), emit fill and dinv (from in-degree cnt_d)
__global__ __launch_bounds__(1024) void scan3b(int* __restrict__ row_ptr,
                                               const int* __restrict__ bsum,
                                               const int* __restrict__ cnt_d,
                                               float* __restrict__ dinv,
                                               int* __restrict__ fill, int n) {
    int i = blockIdx.x * 1024 + threadIdx.x;
    if (i < n) {
        int rp = row_ptr[i] + bsum[blockIdx.x];
        row_ptr[i] = rp;
        fill[i] = rp;
        dinv[i] = rsqrtf((float)cnt_d[i] + 1.0f);
    }
    if (i == 0) row_ptr[n] = EE;
}

// CSR by src: col[] holds dst
__global__ void scatter_src(const int* __restrict__ ei, int* __restrict__ fill,
                            int* __restrict__ col) {
    int e = blockIdx.x * 256 + threadIdx.x;
    if (e < EE) {
        int s = ei[e];
        int d = ei[EE + e];
        int pos = atomicAdd(&fill[s], 1);
        col[pos] = d;
    }
}

// ---------------- U propagation: U_{k+1} = A_hat^T U_k ----------------
// (A_hat^T v)[i] = di^2 v[i] + di * sum_{edges (i->j)} dinv[j] * v[j]
// U0 = graph indicator columns (fused into uprop_first).
__global__ __launch_bounds__(256) void uprop_first(const int* __restrict__ rp,
                                                   const int* __restrict__ col,
                                                   const float* __restrict__ dinv,
                                                   const int* __restrict__ bat,
                                                   float* __restrict__ U) {
    int wid = threadIdx.x >> 6, lane = threadIdx.x & 63;
    int i = blockIdx.x * 4 + wid;
    if (i >= NN) return;
    float di = dinv[i];
    float acc = (bat[i] == lane) ? di * di : 0.f;
    int s = rp[i], e = rp[i + 1];
    for (int t = s; t < e; t++) {
        int d = col[t];
        float w = di * dinv[d];
        acc += (bat[d] == lane) ? w : 0.f;
    }
    U[(size_t)i * 64 + lane] = acc;
}

__global__ __launch_bounds__(256) void uprop_next(const int* __restrict__ rp,
                                                  const int* __restrict__ col,
                                                  const float* __restrict__ dinv,
                                                  const float* __restrict__ Uin,
                                                  float* __restrict__ Uout) {
    int wid = threadIdx.x >> 6, lane = threadIdx.x & 63;
    int i = blockIdx.x * 4 + wid;
    if (i >= NN) return;
    float di = dinv[i];
    float acc = di * di * Uin[(size_t)i * 64 + lane];
    int s = rp[i], e = rp[i + 1];
    int t = s;
    for (; t + 1 < e; t += 2) {
        int d0 = col[t], d1 = col[t + 1];
        float w0 = di * dinv[d0], w1 = di * dinv[d1];
        float u0 = Uin[(size_t)d0 * 64 + lane];
        float u1 = Uin[(size_t)d1 * 64 + lane];
        acc = fmaf(u0, w0, acc);
        acc = fmaf(u1, w1, acc);
    }
    if (t < e) {
        int d0 = col[t];
        acc = fmaf(Uin[(size_t)d0 * 64 + lane], di * dinv[d0], acc);
    }
    Uout[(size_t)i * 64 + lane] = acc;
}

// zero the pad rows [NN, NPAD) of U1/U2/U3 (read by contract)
__global__ void pad_zero(float* __restrict__ U1, float* __restrict__ U2,
                         float* __restrict__ U3) {
    int i = blockIdx.x * 256 + threadIdx.x;
    const int n = (NPAD - NN) * 64;
    if (i < n) {
        size_t o = (size_t)NN * 64 + i;
        U1[o] = 0.f;
        U2[o] = 0.f;
        U3[o] = 0.f;
    }
}

// column sums of U1, U2 -> sigraw[0..63], sigraw[64..127]
__global__ __launch_bounds__(256) void usig_kernel(const float* __restrict__ U1,
                                                   const float* __restrict__ U2,
                                                   float* __restrict__ sigraw) {
    int g = threadIdx.x & 63, rs = threadIdx.x >> 6;
    int r0 = blockIdx.x * 512;
    int rend = min(r0 + 512, NN);
    float a1 = 0.f, a2 = 0.f;
    for (int r = r0 + rs; r < rend; r += 4) {
        size_t o = (size_t)r * 64 + g;
        a1 += U1[o];
        a2 += U2[o];
    }
    __shared__ float sh[2][256];
    sh[0][threadIdx.x] = a1;
    sh[1][threadIdx.x] = a2;
    __syncthreads();
    if (rs == 0) {
        a1 = sh[0][g] + sh[0][64 + g] + sh[0][128 + g] + sh[0][192 + g];
        a2 = sh[1][g] + sh[1][64 + g] + sh[1][128 + g] + sh[1][192 + g];
        atomicAdd(&sigraw[g], a1);
        atomicAdd(&sigraw[64 + g], a2);
    }
}

// ---------------- contraction: Q_k = U_k^T X  (f32, split-K partials) ----------------
// grid (KS, 5, 3): x = k-slice, y = col-tile (256 of 1280), z = which U.
// block tile: 64 g x 256 c, 256 threads -> 8x8 acc per thread.
__global__ __launch_bounds__(256) void contract_kernel(
    const float* __restrict__ X,
    const float* __restrict__ U1, const float* __restrict__ U2,
    const float* __restrict__ U3, float* __restrict__ partial) {
    __shared__ __align__(16) float Us[32 * 64];     // 8 KB
    __shared__ __align__(16) float Xs[32 * 256];    // 32 KB
    const int ks = blockIdx.x, ct = blockIdx.y, gt = blockIdx.z;
    const float* U = (gt == 0) ? U1 : ((gt == 1) ? U2 : U3);
    const int tid = threadIdx.x;
    const int tc = tid & 31, tg = tid >> 5;
    const int r0 = ks * RS;

    float a[8][8];
#pragma unroll
    for (int gg = 0; gg < 8; gg++)
#pragma unroll
        for (int cc = 0; cc < 8; cc++) a[gg][cc] = 0.f;

    for (int ch = 0; ch < RS / 32; ch++) {
        int rb = r0 + ch * 32;
        __syncthreads();
        // U chunk: 32 rows x 64 f = 512 x 16B segs (2/thread). U is padded+zeroed.
#pragma unroll
        for (int i = 0; i < 2; i++) {
            int p = tid + i * 256;
            g2l16(U + (size_t)(rb + (p >> 4)) * 64 + (p & 15) * 4, (char*)Us + p * 16);
        }
        // X chunk: 32 rows x 256 f = 2048 segs (8/thread). Clamp row (U pad=0 kills it).
#pragma unroll
        for (int i = 0; i < 8; i++) {
            int p = tid + i * 256;
            int xr = rb + (p >> 6);
            if (xr > NN - 1) xr = NN - 1;
            g2l16(X + (size_t)xr * INDIM + ct * 256 + (p & 63) * 4, (char*)Xs + p * 16);
        }
        __syncthreads();
#pragma unroll 4
        for (int r = 0; r < 32; r++) {
            float4 u0 = *(const float4*)&Us[r * 64 + tg * 8];
            float4 u1 = *(const float4*)&Us[r * 64 + tg * 8 + 4];
            float4 x0 = *(const float4*)&Xs[r * 256 + tc * 8];
            float4 x1 = *(const float4*)&Xs[r * 256 + tc * 8 + 4];
            float uu[8] = {u0.x, u0.y, u0.z, u0.w, u1.x, u1.y, u1.z, u1.w};
            float xx[8] = {x0.x, x0.y, x0.z, x0.w, x1.x, x1.y, x1.z, x1.w};
#pragma unroll
            for (int gg = 0; gg < 8; gg++)
#pragma unroll
                for (int cc = 0; cc < 8; cc++)
                    a[gg][cc] = fmaf(uu[gg], xx[cc], a[gg][cc]);
        }
    }

    float* pp = partial + (size_t)ks * QSZ;
#pragma unroll
    for (int gg = 0; gg < 8; gg++) {
        int grow = gt * 64 + tg * 8 + gg;
        float* dst = pp + (size_t)grow * INDIM + ct * 256 + tc * 8;
        *(float4*)dst = make_float4(a[gg][0], a[gg][1], a[gg][2], a[gg][3]);
        *(float4*)(dst + 4) = make_float4(a[gg][4], a[gg][5], a[gg][6], a[gg][7]);
    }
}

// reduce split-K partials and fold the per-graph 1/n_g
__global__ void reduce_q(const float* __restrict__ partial, const int* __restrict__ gcnt,
                         float* __restrict__ Q) {
    int o = blockIdx.x * 256 + threadIdx.x;
    if (o >= QSZ) return;
    float a = 0.f;
    for (int ks = 0; ks < KS; ks++) a += partial[(size_t)ks * QSZ + o];
    int g = (o / INDIM) & 63;
    Q[o] = a / (float)max(gcnt[g], 1);
}

// ---------------- R[192 x 512] = Q[192 x 1280] @ W1 ----------------
__global__ __launch_bounds__(256) void gemm_q(const float* __restrict__ Q,
                                              const float* __restrict__ W1,
                                              float* __restrict__ R) {
    __shared__ float a_s[32][33];
    int tid = threadIdx.x;
    int c = blockIdx.x * 64 + (tid & 63);
    int grp = tid >> 6;
    int m0 = blockIdx.y * 32;
    float acc[8];
#pragma unroll
    for (int i = 0; i < 8; i++) acc[i] = 0.f;
    for (int k0 = 0; k0 < INDIM; k0 += 32) {
        __syncthreads();
#pragma unroll
        for (int i = 0; i < 4; i++) {
            int idx = tid + i * 256;
            int row = idx >> 5, kk = idx & 31;
            a_s[row][kk] = Q[(size_t)(m0 + row) * INDIM + k0 + kk];
        }
        __syncthreads();
#pragma unroll
        for (int kk = 0; kk < 32; kk++) {
            float w = W1[(size_t)(k0 + kk) * GD + c];
#pragma unroll
            for (int i = 0; i < 8; i++)
                acc[i] = fmaf(a_s[grp * 8 + i][kk], w, acc[i]);
        }
    }
#pragma unroll
    for (int i = 0; i < 8; i++)
        R[(size_t)(m0 + grp * 8 + i) * GD + c] = acc[i];
}

// ---------------- head algebra prep ----------------
// g1 = R1 + b1 ; t2 = R2 + sig1*b1 ; t3 = R3 + sig2*b1  (R_k = p_k pre-bias)
__global__ __launch_bounds__(256) void head_fix(const float* __restrict__ R,
                                                const float* __restrict__ sigraw,
                                                const int* __restrict__ gcnt,
                                                const float* __restrict__ b1,
                                                float* __restrict__ G,
                                                float* __restrict__ t2,
                                                float* __restrict__ t3,
                                                float* __restrict__ sig1m) {
    int g = blockIdx.x;
    float inv = 1.0f / (float)max(gcnt[g], 1);
    float sg1 = sigraw[g] * inv, sg2 = sigraw[64 + g] * inv;
    if (threadIdx.x == 0) sig1m[g] = sg1;
    for (int c = threadIdx.x; c < GD; c += 256) {
        float b = b1[c];
        G[(size_t)g * CAT + c] = R[(size_t)g * GD + c] + b;
        t2[(size_t)g * GD + c] = R[(size_t)(64 + g) * GD + c] + sg1 * b;
        t3[(size_t)g * GD + c] = R[(size_t)(128 + g) * GD + c] + sg2 * b;
    }
}

// ---------------- small f32 GEMM [64x512] @ [512x512] (+ outer/bias terms) -------
template <bool HAS_SCALE, bool HAS_CVEC>
__global__ __launch_bounds__(256) void small_mm(const float* __restrict__ A,
                                                const float* __restrict__ W,
                                                const float* __restrict__ scale,
                                                const float* __restrict__ bvec,
                                                const float* __restrict__ cvec,
                                                float* __restrict__ out, int ostride) {
    __shared__ float a_s[64][33];
    int tid = threadIdx.x;
    int c = blockIdx.x * 64 + (tid & 63);
    int grp = tid >> 6;
    float acc[16];
#pragma unroll
    for (int i = 0; i < 16; i++) acc[i] = 0.f;
    for (int k0 = 0; k0 < GD; k0 += 32) {
        __syncthreads();
#pragma unroll
        for (int i = 0; i < 8; i++) {
            int idx = tid + i * 256;
            int m = idx >> 5, kk = idx & 31;
            a_s[m][kk] = A[(size_t)m * GD + k0 + kk];
        }
        __syncthreads();
#pragma unroll
        for (int kk = 0; kk < 32; kk++) {
            float w = W[(size_t)(k0 + kk) * GD + c];
#pragma unroll
            for (int i = 0; i < 16; i++)
                acc[i] = fmaf(a_s[grp * 16 + i][kk], w, acc[i]);
        }
    }
    float bv = HAS_SCALE ? bvec[c] : 0.f;
    float cv = HAS_CVEC ? cvec[c] : 0.f;
#pragma unroll
    for (int i = 0; i < 16; i++) {
        int m = grp * 16 + i;
        float v = acc[i] + cv;
        if (HAS_SCALE) v += scale[m] * bv;
        out[(size_t)m * ostride + c] = v;
    }
}

// ---------------- small FC: out[64 x NOUT] = act(A[64 x K] @ W + b) ----------------
template <int K, int NOUT, bool RELU>
__global__ __launch_bounds__(256) void fc_kernel(const float* __restrict__ A,
                                                 const float* __restrict__ W,
                                                 const float* __restrict__ bias,
                                                 float* __restrict__ out) {
    __shared__ float a_s[64][33];
    int tid = threadIdx.x;
    int c = blockIdx.x * 64 + (tid & 63);
    int grp = tid >> 6;
    float acc[16];
#pragma unroll
    for (int i = 0; i < 16; i++) acc[i] = 0.f;
    for (int k0 = 0; k0 < K; k0 += 32) {
        __syncthreads();
#pragma unroll
        for (int i = 0; i < 8; i++) {
            int idx = tid + i * 256;
            int m = idx >> 5, kk = idx & 31;
            a_s[m][kk] = A[(size_t)m * K + k0 + kk];
        }
        __syncthreads();
#pragma unroll
        for (int kk = 0; kk < 32; kk++) {
            float w = W[(size_t)(k0 + kk) * NOUT + c];
#pragma unroll
            for (int i = 0; i < 16; i++)
                acc[i] = fmaf(a_s[grp * 16 + i][kk], w, acc[i]);
        }
    }
    float b = bias[c];
#pragma unroll
    for (int i = 0; i < 16; i++) {
        float v = acc[i] + b;
        if (RELU) v = fmaxf(v, 0.f);
        out[(size_t)(grp * 16 + i) * NOUT + c] = v;
    }
}

// ---------------- launch ----------------
static inline size_t al256(size_t x) { return (x + 255) & ~(size_t)255; }

extern "C" void kernel_launch(void* const* d_in, const int* in_sizes, int n_in,
                              void* d_out, int out_size, void* d_ws, size_t ws_size,
                              hipStream_t stream) {
    const float* x   = (const float*)d_in[0];
    const int*   ei  = (const int*)d_in[1];
    const int*   bat = (const int*)d_in[2];
    const float* Wg1 = (const float*)d_in[3];
    const float* bg1 = (const float*)d_in[4];
    const float* Wg2 = (const float*)d_in[5];
    const float* bg2 = (const float*)d_in[6];
    const float* Wg3 = (const float*)d_in[7];
    const float* bg3 = (const float*)d_in[8];
    const float* Wr  = (const float*)d_in[9];
    const float* br  = (const float*)d_in[10];
    const float* Wf  = (const float*)d_in[11];
    const float* bf  = (const float*)d_in[12];
    const float* Wo  = (const float*)d_in[13];
    const float* bo  = (const float*)d_in[14];
    float* out = (float*)d_out;

    char* ws = (char*)d_ws;
    size_t off = 0;
    int*   cnt2    = (int*)(ws + off); off += al256((size_t)2 * NN * 4);   // cnt_s | cnt_d
    int*   row_ptr = (int*)(ws + off); off += al256((size_t)(NN + 1) * 4);
    int*   fill    = (int*)(ws + off); off += al256((size_t)NN * 4);
    float* dinv    = (float*)(ws + off); off += al256((size_t)NN * 4);
    int*   col     = (int*)(ws + off); off += al256((size_t)EE * 4);
    int*   bsum    = (int*)(ws + off); off += al256(64 * 4);
    int*   smallz  = (int*)(ws + off); off += al256(512 * 4);              // gcnt|sigraw|sig1m
    float* U1      = (float*)(ws + off); off += al256((size_t)NPAD * 64 * 4);
    float* U2      = (float*)(ws + off); off += al256((size_t)NPAD * 64 * 4);
    float* U3      = (float*)(ws + off); off += al256((size_t)NPAD * 64 * 4);
    float* partial = (float*)(ws + off); off += al256((size_t)KS * QSZ * 4);
    float* Q       = (float*)(ws + off); off += al256((size_t)QSZ * 4);
    float* R       = (float*)(ws + off); off += al256((size_t)192 * GD * 4);
    float* G       = (float*)(ws + off); off += al256((size_t)NG * CAT * 4);
    float* t2      = (float*)(ws + off); off += al256((size_t)NG * GD * 4);
    float* t3      = (float*)(ws + off); off += al256((size_t)NG * GD * 4);
    float* u3      = (float*)(ws + off); off += al256((size_t)NG * GD * 4);
    float* r0      = (float*)(ws + off); off += al256((size_t)NG * FC0D * 4);
    float* r1      = (float*)(ws + off); off += al256((size_t)NG * FC1D * 4);
    (void)ws_size; (void)n_in; (void)in_sizes; (void)out_size;

    int*   cnt_s = cnt2;
    int*   cnt_d = cnt2 + NN;
    int*   gcnt  = smallz;                    // 64 ints
    float* sigraw = (float*)(smallz + 64);    // 128 floats (sig1 raw | sig2 raw)
    float* sig1m  = (float*)(smallz + 192);   // 64 floats

    const int nscan = (NN + 1023) / 1024;

    // zeros
    zero_u32<<<dim3((2 * NN + 255) / 256), 256, 0, stream>>>((uint32_t*)cnt2, 2 * NN);
    zero_u32<<<dim3(1), 256, 0, stream>>>((uint32_t*)smallz, 256);

    // degree histograms + graph sizes
    hist_edges<<<dim3((EE + 255) / 256), 256, 0, stream>>>(ei, cnt_s, cnt_d);
    count_batch<<<dim3((NN + 255) / 256), 256, 0, stream>>>(bat, gcnt);

    // CSR by src
    scan1<<<dim3(nscan), 1024, 0, stream>>>(cnt_s, row_ptr, bsum, NN);
    scan2<<<dim3(1), 64, 0, stream>>>(bsum, nscan);
    scan3b<<<dim3(nscan), 1024, 0, stream>>>(row_ptr, bsum, cnt_d, dinv, fill, NN);
    scatter_src<<<dim3((EE + 255) / 256), 256, 0, stream>>>(ei, fill, col);

    // U propagation (A_hat^T powers of graph indicators)
    dim3 ugrid(NN / 4);
    uprop_first<<<ugrid, 256, 0, stream>>>(row_ptr, col, dinv, bat, U1);
    uprop_next<<<ugrid, 256, 0, stream>>>(row_ptr, col, dinv, U1, U2);
    uprop_next<<<ugrid, 256, 0, stream>>>(row_ptr, col, dinv, U2, U3);
    pad_zero<<<dim3(((NPAD - NN) * 64 + 255) / 256), 256, 0, stream>>>(U1, U2, U3);

    // sigma_1/2 raw column sums
    usig_kernel<<<dim3((NN + 511) / 512), 256, 0, stream>>>(U1, U2, sigraw);

    // Q_k = U_k^T X  (split-K partials -> reduce with 1/n_g folded)
    contract_kernel<<<dim3(KS, INDIM / 256, 3), 256, 0, stream>>>(x, U1, U2, U3, partial);
    reduce_q<<<dim3((QSZ + 255) / 256), 256, 0, stream>>>(partial, gcnt, Q);

    // R = Q @ W1  -> p1|p2|p3 pre-bias
    gemm_q<<<dim3(GD / 64, 6), 256, 0, stream>>>(Q, Wg1, R);

    // head algebra:
    // g1 = p1 + b1 ; g2 = (p2 + s1 b1) W2 + b2 ; g3 = ((p3 + s2 b1) W2 + s1 b2) W3 + b3
    head_fix<<<dim3(NG), 256, 0, stream>>>(R, sigraw, gcnt, bg1, G, t2, t3, sig1m);
    small_mm<false, true><<<dim3(GD / 64), 256, 0, stream>>>(t2, Wg2, nullptr, nullptr, bg2, G + GD, CAT);
    small_mm<true, false><<<dim3(GD / 64), 256, 0, stream>>>(t3, Wg2, sig1m, bg2, nullptr, u3, GD);
    small_mm<false, true><<<dim3(GD / 64), 256, 0, stream>>>(u3, Wg3, nullptr, nullptr, bg3, G + 2 * GD, CAT);

    // FC head
    fc_kernel<CAT, FC0D, true><<<dim3(FC0D / 64), 256, 0, stream>>>(G, Wr, br, r0);
    fc_kernel<FC0D, FC1D, true><<<dim3(FC1D / 64), 256, 0, stream>>>(r0, Wf, bf, r1);
    fc_kernel<FC1D, OUTD, false><<<dim3(OUTD / 64), 256, 0, stream>>>(r1, Wo, bo, out);
}

// Round 6
// 1593.983 us; speedup vs baseline: 1.1493x; 1.1031x over previous
//
#include <hip/hip_runtime.h>
#include <stdint.h>

// Problem constants (fixed by the reference)
#define NN 50000
#define EE 800000
#define INDIM 1280
#define GD 512
#define CAT 1536
#define FC0D 1024
#define FC1D 512
#define OUTD 256
#define NG 64

// contraction split-K geometry
#define KS 74
#define RS 704                  // KS*RS = 52096 >= NN, RS % 32 == 0
#define NPAD (KS * RS)          // 52096
#define QSZ (192 * INDIM)       // 245760
#define CTS 128                 // contract col-tile

__device__ __forceinline__ void g2l16(const void* g, void* l) {
    __builtin_amdgcn_global_load_lds(
        (const __attribute__((address_space(1))) void*)g,
        (__attribute__((address_space(3))) void*)l, 16, 0, 0);
}

// ---------------- utility kernels ----------------
__global__ void zero_u32(uint32_t* p, int n) {
    int i = blockIdx.x * 256 + threadIdx.x;
    if (i < n) p[i] = 0u;
}

// count out-degree (by src) for CSR and in-degree (by dst) for dinv
__global__ void hist_edges(const int* __restrict__ ei, int* __restrict__ cnt_s,
                           int* __restrict__ cnt_d) {
    int e = blockIdx.x * 256 + threadIdx.x;
    if (e < EE) {
        atomicAdd(&cnt_s[ei[e]], 1);
        atomicAdd(&cnt_d[ei[EE + e]], 1);
    }
}

// batch is sorted -> per-graph counts via binary search (no atomics)
__global__ void batch_bounds(const int* __restrict__ bat, int* __restrict__ gcnt) {
    int g = threadIdx.x;   // 0..63
    int lo = 0, hi = NN;
    while (lo < hi) {
        int mid = (lo + hi) >> 1;
        if (bat[mid] < g) lo = mid + 1; else hi = mid;
    }
    int nxt = __shfl_down(lo, 1);
    if (g == 63) nxt = NN;
    gcnt[g] = nxt - lo;
}

__global__ __launch_bounds__(1024) void scan1(const int* __restrict__ cnt,
                                              int* __restrict__ row_ptr,
                                              int* __restrict__ bsum, int n) {
    __shared__ int s[1024];
    int tid = threadIdx.x;
    int i = blockIdx.x * 1024 + tid;
    int v = (i < n) ? cnt[i] : 0;
    s[tid] = v;
    __syncthreads();
    for (int off = 1; off < 1024; off <<= 1) {
        int t = 0;
        if (tid >= off) t = s[tid - off];
        __syncthreads();
        if (tid >= off) s[tid] += t;
        __syncthreads();
    }
    if (i < n) row_ptr[i] = s[tid] - v;
    if (tid == 1023) bsum[blockIdx.x] = s[1023];
}

// wave-parallel exclusive scan of nb (<=64) block sums
__global__ void scan2(int* bsum, int nb) {
    int i = threadIdx.x;
    int v = (i < nb) ? bsum[i] : 0;
    int s = v;
#pragma unroll
    for (int off = 1; off < 64; off <<= 1) {
        int t = __shfl_up(s, off);
        if (i >= off) s += t;
    }
    if (i < nb) bsum[i] = s - v;
}

// finalize row_ptr (by src), emit fill and dinv (from in-degree cnt_d)
__global__ __launch_bounds__(1024) void scan3b(int* __restrict__ row_ptr,
                                               const int* __restrict__ bsum,
                                               const int* __restrict__ cnt_d,
                                               float* __restrict__ dinv,
                                               int* __restrict__ fill, int n) {
    int i = blockIdx.x * 1024 + threadIdx.x;
    if (i < n) {
        int rp = row_ptr[i] + bsum[blockIdx.x];
        row_ptr[i] = rp;
        fill[i] = rp;
        dinv[i] = rsqrtf((float)cnt_d[i] + 1.0f);
    }
    if (i == 0) row_ptr[n] = EE;
}

// CSR by src: col[] holds dst
__global__ void scatter_src(const int* __restrict__ ei, int* __restrict__ fill,
                            int* __restrict__ col) {
    int e = blockIdx.x * 256 + threadIdx.x;
    if (e < EE) {
        int s = ei[e];
        int d = ei[EE + e];
        int pos = atomicAdd(&fill[s], 1);
        col[pos] = d;
    }
}

// ---------------- U propagation: U_{k+1} = A_hat^T U_k ----------------
// (A_hat^T v)[i] = di^2 v[i] + di * sum_{edges (i->j)} dinv[j] * v[j]
// grid covers NPAD rows; rows >= NN are zero-filled (pad for contract).
__global__ __launch_bounds__(256) void uprop_first(const int* __restrict__ rp,
                                                   const int* __restrict__ col,
                                                   const float* __restrict__ dinv,
                                                   const int* __restrict__ bat,
                                                   float* __restrict__ U) {
    int wid = threadIdx.x >> 6, lane = threadIdx.x & 63;
    int i = blockIdx.x * 4 + wid;
    if (i >= NPAD) return;
    if (i >= NN) { U[(size_t)i * 64 + lane] = 0.f; return; }
    float di = dinv[i];
    float acc = (bat[i] == lane) ? di * di : 0.f;
    int s = rp[i], e = rp[i + 1];
    for (int t = s; t < e; t++) {
        int d = col[t];
        float w = di * dinv[d];
        acc += (bat[d] == lane) ? w : 0.f;
    }
    U[(size_t)i * 64 + lane] = acc;
}

__global__ __launch_bounds__(256) void uprop_next(const int* __restrict__ rp,
                                                  const int* __restrict__ col,
                                                  const float* __restrict__ dinv,
                                                  const float* __restrict__ Uin,
                                                  float* __restrict__ Uout) {
    int wid = threadIdx.x >> 6, lane = threadIdx.x & 63;
    int i = blockIdx.x * 4 + wid;
    if (i >= NPAD) return;
    if (i >= NN) { Uout[(size_t)i * 64 + lane] = 0.f; return; }
    float di = dinv[i];
    float acc = di * di * Uin[(size_t)i * 64 + lane];
    int s = rp[i], e = rp[i + 1];
    int t = s;
    for (; t + 1 < e; t += 2) {
        int d0 = col[t], d1 = col[t + 1];
        float w0 = di * dinv[d0], w1 = di * dinv[d1];
        float u0 = Uin[(size_t)d0 * 64 + lane];
        float u1 = Uin[(size_t)d1 * 64 + lane];
        acc = fmaf(u0, w0, acc);
        acc = fmaf(u1, w1, acc);
    }
    if (t < e) {
        int d0 = col[t];
        acc = fmaf(Uin[(size_t)d0 * 64 + lane], di * dinv[d0], acc);
    }
    Uout[(size_t)i * 64 + lane] = acc;
}

// column sums of U1, U2 -> sigraw[0..63], sigraw[64..127]
__global__ __launch_bounds__(256) void usig_kernel(const float* __restrict__ U1,
                                                   const float* __restrict__ U2,
                                                   float* __restrict__ sigraw) {
    int g = threadIdx.x & 63, rs = threadIdx.x >> 6;
    int r0 = blockIdx.x * 512;
    int rend = min(r0 + 512, NN);
    float a1 = 0.f, a2 = 0.f;
    for (int r = r0 + rs; r < rend; r += 4) {
        size_t o = (size_t)r * 64 + g;
        a1 += U1[o];
        a2 += U2[o];
    }
    __shared__ float sh[2][256];
    sh[0][threadIdx.x] = a1;
    sh[1][threadIdx.x] = a2;
    __syncthreads();
    if (rs == 0) {
        a1 = sh[0][g] + sh[0][64 + g] + sh[0][128 + g] + sh[0][192 + g];
        a2 = sh[1][g] + sh[1][64 + g] + sh[1][128 + g] + sh[1][192 + g];
        atomicAdd(&sigraw[g], a1);
        atomicAdd(&sigraw[64 + g], a2);
    }
}

// ---------------- contraction: Q = [U1|U2|U3]^T X  (f32, split-K partials) ----------
// grid (KS, INDIM/CTS). Block tile 192 g x 128 c, 256 threads -> 96 acc/thread.
// All three U's per block: X is staged/read ONCE.
#define FMA4(A, s) \
    A.x = fmaf(s, xv.x, A.x); A.y = fmaf(s, xv.y, A.y); \
    A.z = fmaf(s, xv.z, A.z); A.w = fmaf(s, xv.w, A.w);

__global__ __launch_bounds__(256) void contract_kernel(
    const float* __restrict__ X,
    const float* __restrict__ U1, const float* __restrict__ U2,
    const float* __restrict__ U3, float* __restrict__ partial) {
    __shared__ __align__(16) float Us[3 * 32 * 64];   // 24 KB
    __shared__ __align__(16) float Xs[32 * CTS];      // 16 KB
    const int ks = blockIdx.x, ct = blockIdx.y;
    const int tid = threadIdx.x;
    const int tc = tid & 31;        // c-group: 4 floats each
    const int tg = tid >> 5;        // g-octet (0..7) within each U
    const int r0 = ks * RS;
    const int ctc = ct * CTS;
    const float* Up[3] = {U1, U2, U3};

    float4 acc[3][8];
#pragma unroll
    for (int u = 0; u < 3; u++)
#pragma unroll
        for (int gg = 0; gg < 8; gg++) acc[u][gg] = make_float4(0.f, 0.f, 0.f, 0.f);

    // staging geometry (precomputed per thread)
    int urow[2], ucol[2], xrow[4], xcol[4];
#pragma unroll
    for (int i = 0; i < 2; i++) {
        int p = tid + i * 256;
        urow[i] = p >> 4;           // 16 segs per 64-f row
        ucol[i] = (p & 15) * 4;
    }
#pragma unroll
    for (int i = 0; i < 4; i++) {
        int p = tid + i * 256;
        xrow[i] = p >> 5;           // 32 segs per 128-f row
        xcol[i] = (p & 31) * 4;
    }

    for (int ch = 0; ch < RS / 32; ch++) {
        int rb = r0 + ch * 32;
        __syncthreads();
#pragma unroll
        for (int u = 0; u < 3; u++)
#pragma unroll
            for (int i = 0; i < 2; i++) {
                g2l16(Up[u] + (size_t)(rb + urow[i]) * 64 + ucol[i],
                      (char*)Us + u * 8192 + (tid + i * 256) * 16);
            }
#pragma unroll
        for (int i = 0; i < 4; i++) {
            int xr = rb + xrow[i];
            if (xr >= NN) xr = NN - 1;   // pad rows: U is zero there
            g2l16(X + (size_t)xr * INDIM + ctc + xcol[i],
                  (char*)Xs + (tid + i * 256) * 16);
        }
        __syncthreads();
#pragma unroll 2
        for (int r = 0; r < 32; r++) {
            float4 xv = *(const float4*)&Xs[r * CTS + tc * 4];
#pragma unroll
            for (int u = 0; u < 3; u++) {
                float4 ua = *(const float4*)&Us[u * 2048 + r * 64 + tg * 8];
                float4 ub = *(const float4*)&Us[u * 2048 + r * 64 + tg * 8 + 4];
                FMA4(acc[u][0], ua.x) FMA4(acc[u][1], ua.y)
                FMA4(acc[u][2], ua.z) FMA4(acc[u][3], ua.w)
                FMA4(acc[u][4], ub.x) FMA4(acc[u][5], ub.y)
                FMA4(acc[u][6], ub.z) FMA4(acc[u][7], ub.w)
            }
        }
    }

    float* pp = partial + (size_t)ks * QSZ;
#pragma unroll
    for (int u = 0; u < 3; u++)
#pragma unroll
        for (int gg = 0; gg < 8; gg++) {
            int grow = u * 64 + tg * 8 + gg;
            *(float4*)(pp + (size_t)grow * INDIM + ctc + tc * 4) = acc[u][gg];
        }
}

// reduce split-K partials and fold the per-graph 1/n_g
__global__ void reduce_q(const float* __restrict__ partial, const int* __restrict__ gcnt,
                         float* __restrict__ Q) {
    int o = blockIdx.x * 256 + threadIdx.x;
    if (o >= QSZ) return;
    float a = 0.f;
    for (int ks = 0; ks < KS; ks++) a += partial[(size_t)ks * QSZ + o];
    int g = (o / INDIM) & 63;
    Q[o] = a / (float)max(gcnt[g], 1);
}

// ---------------- R = Q @ W1 with head-algebra epilogue fused --------------------
// rows 0..63 -> G[:, :512] = v + b1 ; rows 64..127 -> t2 = v + sig1*b1 ;
// rows 128..191 -> t3 = v + sig2*b1
__global__ __launch_bounds__(256) void gemm_qh(const float* __restrict__ Q,
                                               const float* __restrict__ W1,
                                               const float* __restrict__ sigraw,
                                               const int* __restrict__ gcnt,
                                               const float* __restrict__ b1,
                                               float* __restrict__ G,
                                               float* __restrict__ t2,
                                               float* __restrict__ t3) {
    __shared__ float a_s[32][33];
    int tid = threadIdx.x;
    int c = blockIdx.x * 64 + (tid & 63);
    int grp = tid >> 6;
    int m0 = blockIdx.y * 32;
    float acc[8];
#pragma unroll
    for (int i = 0; i < 8; i++) acc[i] = 0.f;
    for (int k0 = 0; k0 < INDIM; k0 += 32) {
        __syncthreads();
#pragma unroll
        for (int i = 0; i < 4; i++) {
            int idx = tid + i * 256;
            int row = idx >> 5, kk = idx & 31;
            a_s[row][kk] = Q[(size_t)(m0 + row) * INDIM + k0 + kk];
        }
        __syncthreads();
#pragma unroll
        for (int kk = 0; kk < 32; kk++) {
            float w = W1[(size_t)(k0 + kk) * GD + c];
#pragma unroll
            for (int i = 0; i < 8; i++)
                acc[i] = fmaf(a_s[grp * 8 + i][kk], w, acc[i]);
        }
    }
    float bc = b1[c];
#pragma unroll
    for (int i = 0; i < 8; i++) {
        int m = m0 + grp * 8 + i;
        float v = acc[i];
        if (m < 64) {
            G[(size_t)m * CAT + c] = v + bc;
        } else if (m < 128) {
            int g = m - 64;
            float inv = 1.0f / (float)max(gcnt[g], 1);
            t2[(size_t)g * GD + c] = v + sigraw[g] * inv * bc;
        } else {
            int g = m - 128;
            float inv = 1.0f / (float)max(gcnt[g], 1);
            t3[(size_t)g * GD + c] = v + sigraw[64 + g] * inv * bc;
        }
    }
}

// ---------------- dual small GEMM vs W2: G2 = t2@W2 + b2 ; u3 = t3@W2 + sig1*b2 ----
__global__ __launch_bounds__(256) void mm_dual(const float* __restrict__ t2,
                                               const float* __restrict__ t3,
                                               const float* __restrict__ W2,
                                               const float* __restrict__ b2,
                                               const float* __restrict__ sigraw,
                                               const int* __restrict__ gcnt,
                                               float* __restrict__ G,
                                               float* __restrict__ u3) {
    __shared__ float a0[64][33], a1[64][33];
    int tid = threadIdx.x;
    int c = blockIdx.x * 64 + (tid & 63);
    int grp = tid >> 6;
    float acc0[16], acc1[16];
#pragma unroll
    for (int i = 0; i < 16; i++) { acc0[i] = 0.f; acc1[i] = 0.f; }
    for (int k0 = 0; k0 < GD; k0 += 32) {
        __syncthreads();
#pragma unroll
        for (int i = 0; i < 8; i++) {
            int idx = tid + i * 256;
            int m = idx >> 5, kk = idx & 31;
            a0[m][kk] = t2[(size_t)m * GD + k0 + kk];
            a1[m][kk] = t3[(size_t)m * GD + k0 + kk];
        }
        __syncthreads();
#pragma unroll
        for (int kk = 0; kk < 32; kk++) {
            float w = W2[(size_t)(k0 + kk) * GD + c];
#pragma unroll
            for (int i = 0; i < 16; i++) {
                acc0[i] = fmaf(a0[grp * 16 + i][kk], w, acc0[i]);
                acc1[i] = fmaf(a1[grp * 16 + i][kk], w, acc1[i]);
            }
        }
    }
    float bc = b2[c];
#pragma unroll
    for (int i = 0; i < 16; i++) {
        int m = grp * 16 + i;
        G[(size_t)m * CAT + GD + c] = acc0[i] + bc;
        float sg1 = sigraw[m] / (float)max(gcnt[m], 1);
        u3[(size_t)m * GD + c] = acc1[i] + sg1 * bc;
    }
}

// ---------------- small f32 GEMM [64x512] @ [512x512] + bias -------------------
__global__ __launch_bounds__(256) void mm_last(const float* __restrict__ A,
                                               const float* __restrict__ W,
                                               const float* __restrict__ cvec,
                                               float* __restrict__ out, int ostride) {
    __shared__ float a_s[64][33];
    int tid = threadIdx.x;
    int c = blockIdx.x * 64 + (tid & 63);
    int grp = tid >> 6;
    float acc[16];
#pragma unroll
    for (int i = 0; i < 16; i++) acc[i] = 0.f;
    for (int k0 = 0; k0 < GD; k0 += 32) {
        __syncthreads();
#pragma unroll
        for (int i = 0; i < 8; i++) {
            int idx = tid + i * 256;
            int m = idx >> 5, kk = idx & 31;
            a_s[m][kk] = A[(size_t)m * GD + k0 + kk];
        }
        __syncthreads();
#pragma unroll
        for (int kk = 0; kk < 32; kk++) {
            float w = W[(size_t)(k0 + kk) * GD + c];
#pragma unroll
            for (int i = 0; i < 16; i++)
                acc[i] = fmaf(a_s[grp * 16 + i][kk], w, acc[i]);
        }
    }
    float cv = cvec[c];
#pragma unroll
    for (int i = 0; i < 16; i++) {
        int m = grp * 16 + i;
        out[(size_t)m * ostride + c] = acc[i] + cv;
    }
}

// ---------------- small FC: out[64 x NOUT] = act(A[64 x K] @ W + b) ----------------
template <int K, int NOUT, bool RELU>
__global__ __launch_bounds__(256) void fc_kernel(const float* __restrict__ A,
                                                 const float* __restrict__ W,
                                                 const float* __restrict__ bias,
                                                 float* __restrict__ out) {
    __shared__ float a_s[64][33];
    int tid = threadIdx.x;
    int c = blockIdx.x * 64 + (tid & 63);
    int grp = tid >> 6;
    float acc[16];
#pragma unroll
    for (int i = 0; i < 16; i++) acc[i] = 0.f;
    for (int k0 = 0; k0 < K; k0 += 32) {
        __syncthreads();
#pragma unroll
        for (int i = 0; i < 8; i++) {
            int idx = tid + i * 256;
            int m = idx >> 5, kk = idx & 31;
            a_s[m][kk] = A[(size_t)m * K + k0 + kk];
        }
        __syncthreads();
#pragma unroll
        for (int kk = 0; kk < 32; kk++) {
            float w = W[(size_t)(k0 + kk) * NOUT + c];
#pragma unroll
            for (int i = 0; i < 16; i++)
                acc[i] = fmaf(a_s[grp * 16 + i][kk], w, acc[i]);
        }
    }
    float b = bias[c];
#pragma unroll
    for (int i = 0; i < 16; i++) {
        float v = acc[i] + b;
        if (RELU) v = fmaxf(v, 0.f);
        out[(size_t)(grp * 16 + i) * NOUT + c] = v;
    }
}

// ---------------- launch ----------------
static inline size_t al256(size_t x) { return (x + 255) & ~(size_t)255; }

extern "C" void kernel_launch(void* const* d_in, const int* in_sizes, int n_in,
                              void* d_out, int out_size, void* d_ws, size_t ws_size,
                              hipStream_t stream) {
    const float* x   = (const float*)d_in[0];
    const int*   ei  = (const int*)d_in[1];
    const int*   bat = (const int*)d_in[2];
    const float* Wg1 = (const float*)d_in[3];
    const float* bg1 = (const float*)d_in[4];
    const float* Wg2 = (const float*)d_in[5];
    const float* bg2 = (const float*)d_in[6];
    const float* Wg3 = (const float*)d_in[7];
    const float* bg3 = (const float*)d_in[8];
    const float* Wr  = (const float*)d_in[9];
    const float* br  = (const float*)d_in[10];
    const float* Wf  = (const float*)d_in[11];
    const float* bf  = (const float*)d_in[12];
    const float* Wo  = (const float*)d_in[13];
    const float* bo  = (const float*)d_in[14];
    float* out = (float*)d_out;

    char* ws = (char*)d_ws;
    size_t off = 0;
    // cnt_s | cnt_d | smallz contiguous -> one zero launch
    int*   cnt2    = (int*)(ws + off); off += al256(((size_t)2 * NN + 512) * 4);
    int*   row_ptr = (int*)(ws + off); off += al256((size_t)(NN + 1) * 4);
    int*   fill    = (int*)(ws + off); off += al256((size_t)NN * 4);
    float* dinv    = (float*)(ws + off); off += al256((size_t)NN * 4);
    int*   col     = (int*)(ws + off); off += al256((size_t)EE * 4);
    int*   bsum    = (int*)(ws + off); off += al256(64 * 4);
    float* U1      = (float*)(ws + off); off += al256((size_t)NPAD * 64 * 4);
    float* U2      = (float*)(ws + off); off += al256((size_t)NPAD * 64 * 4);
    float* U3      = (float*)(ws + off); off += al256((size_t)NPAD * 64 * 4);
    float* partial = (float*)(ws + off); off += al256((size_t)KS * QSZ * 4);
    float* Q       = (float*)(ws + off); off += al256((size_t)QSZ * 4);
    float* G       = (float*)(ws + off); off += al256((size_t)NG * CAT * 4);
    float* t2      = (float*)(ws + off); off += al256((size_t)NG * GD * 4);
    float* t3      = (float*)(ws + off); off += al256((size_t)NG * GD * 4);
    float* u3      = (float*)(ws + off); off += al256((size_t)NG * GD * 4);
    float* r0      = (float*)(ws + off); off += al256((size_t)NG * FC0D * 4);
    float* r1      = (float*)(ws + off); off += al256((size_t)NG * FC1D * 4);
    (void)ws_size; (void)n_in; (void)in_sizes; (void)out_size;

    int*   cnt_s  = cnt2;
    int*   cnt_d  = cnt2 + NN;
    int*   gcnt   = cnt2 + 2 * NN;            // 64 ints
    float* sigraw = (float*)(cnt2 + 2 * NN + 64);   // 128 floats

    const int nscan = (NN + 1023) / 1024;

    // zeros (cnt_s, cnt_d, gcnt, sigraw in one region)
    zero_u32<<<dim3((2 * NN + 512 + 255) / 256), 256, 0, stream>>>((uint32_t*)cnt2, 2 * NN + 512);

    // degree histograms + graph sizes (binary search on sorted batch)
    hist_edges<<<dim3((EE + 255) / 256), 256, 0, stream>>>(ei, cnt_s, cnt_d);
    batch_bounds<<<dim3(1), 64, 0, stream>>>(bat, gcnt);

    // CSR by src
    scan1<<<dim3(nscan), 1024, 0, stream>>>(cnt_s, row_ptr, bsum, NN);
    scan2<<<dim3(1), 64, 0, stream>>>(bsum, nscan);
    scan3b<<<dim3(nscan), 1024, 0, stream>>>(row_ptr, bsum, cnt_d, dinv, fill, NN);
    scatter_src<<<dim3((EE + 255) / 256), 256, 0, stream>>>(ei, fill, col);

    // U propagation (A_hat^T powers of graph indicators), pads zero-filled
    dim3 ugrid(NPAD / 4);
    uprop_first<<<ugrid, 256, 0, stream>>>(row_ptr, col, dinv, bat, U1);
    uprop_next<<<ugrid, 256, 0, stream>>>(row_ptr, col, dinv, U1, U2);
    uprop_next<<<ugrid, 256, 0, stream>>>(row_ptr, col, dinv, U2, U3);

    // sigma_1/2 raw column sums
    usig_kernel<<<dim3((NN + 511) / 512), 256, 0, stream>>>(U1, U2, sigraw);

    // Q = [U1|U2|U3]^T X  (X read once; split-K partials -> reduce with 1/n_g)
    contract_kernel<<<dim3(KS, INDIM / CTS), 256, 0, stream>>>(x, U1, U2, U3, partial);
    reduce_q<<<dim3((QSZ + 255) / 256), 256, 0, stream>>>(partial, gcnt, Q);

    // R = Q @ W1 with fused head algebra -> G[:, :512], t2, t3
    gemm_qh<<<dim3(GD / 64, 6), 256, 0, stream>>>(Q, Wg1, sigraw, gcnt, bg1, G, t2, t3);
    // G2 = t2@W2 + b2 ; u3 = t3@W2 + sig1*b2   (one pass over W2)
    mm_dual<<<dim3(GD / 64), 256, 0, stream>>>(t2, t3, Wg2, bg2, sigraw, gcnt, G, u3);
    // G3 = u3@W3 + b3
    mm_last<<<dim3(GD / 64), 256, 0, stream>>>(u3, Wg3, bg3, G + 2 * GD, CAT);

    // FC head
    fc_kernel<CAT, FC0D, true><<<dim3(FC0D / 64), 256, 0, stream>>>(G, Wr, br, r0);
    fc_kernel<FC0D, FC1D, true><<<dim3(FC1D / 64), 256, 0, stream>>>(r0, Wf, bf, r1);
    fc_kernel<FC1D, OUTD, false><<<dim3(OUTD / 64), 256, 0, stream>>>(r1, Wo, bo, out);
}